// Round 1
// baseline (535.733 us; speedup 1.0000x reference)
//
#include <hip/hip_runtime.h>
#include <hip/hip_bf16.h>

// Problem constants: B=1, S=1024, D=1024, F=4096, E=8
#define TOK 1024
#define DIM 1024
#define FF  4096
#define NE  8
#define EPSV 1e-5f
#define BUCKET_STRIDE 1040   // >= max padded bucket (ceil(1024/128)*128 = 1024)
#define MAXT 16              // max tiles of 128: sum ceil(n_e/128) <= 1024/128 + 8 = 16

typedef __attribute__((ext_vector_type(8))) short short8;   // 8 bf16 = 4 VGPRs
typedef __attribute__((ext_vector_type(4))) float floatx4;

// -------- workspace layout (bytes) -- no weight-conversion buffers anymore --------
#define OFF_HNORM  0
#define OFF_H1     (OFF_HNORM + (size_t)TOK*DIM*2)
#define OFF_ALPHA  (OFF_H1 + (size_t)TOK*FF*2)
#define OFF_CNT    (OFF_ALPHA + TOK*4)
#define OFF_NT     (OFF_CNT + NE*4)
#define OFF_TILES  (OFF_NT + 4)
#define OFF_BUCKET (OFF_TILES + 64*4)
#define OFF_FLAGS  (OFF_BUCKET + NE*BUCKET_STRIDE*4)   // 9 ints (16 reserved)

struct Ptr8 { const void* p[8]; };

// ---- dual-dtype helpers (flag: 1 = buffer is float32, 0 = bf16) ----
__device__ __forceinline__ float ldf(const void* p, size_t i, int f32) {
    if (f32) return ((const float*)p)[i];
    union { unsigned u; float f; } v;
    v.u = ((unsigned)((const unsigned short*)p)[i]) << 16;
    return v.f;
}

__device__ __forceinline__ short bf16rne(float f) {
    unsigned u = __float_as_uint(f);
    return (short)((u + 0x7FFFu + ((u >> 16) & 1u)) >> 16);
}

// Fragment loader, dtype resolved at COMPILE time (kernel unswitched on flag).
template<int F32>
__device__ __forceinline__ short8 ldfrag8T(const void* p, size_t i) {
    if (F32) {
        const floatx4* fp = (const floatx4*)((const float*)p + i);
        const floatx4 a = fp[0], b = fp[1];
        short8 r;
        #pragma unroll
        for (int j = 0; j < 4; j++) { r[j] = bf16rne(a[j]); r[4 + j] = bf16rne(b[j]); }
        return r;
    } else {
        return *(const short8*)((const short*)p + i);
    }
}

__device__ __forceinline__ void stout(void* p, size_t i, float v, int f32) {
    if (f32) ((float*)p)[i] = v;
    else ((__hip_bfloat16*)p)[i] = __float2bfloat16(v);
}

// Zero cnt + classify each input buffer's dtype by bit-pattern scan.
__global__ void k_init(Ptr8 ptrs, int* __restrict__ cnt, int* __restrict__ flags) {
    const int tid = threadIdx.x;
    if (tid < NE) cnt[tid] = 0;
    if (tid < 8) {
        const unsigned* w = (const unsigned*)ptrs.p[tid];
        int f32 = 0;
        for (int i = 0; i < 64; i++) {
            const unsigned v = w[i];
            if (v == 0x3F800000u) { f32 = 1; break; }   // exact f32 1.0 (e.g. gamma=ones)
            const unsigned lo = v & 0xFFFFu;
            if (lo != 0) {
                const unsigned e = (lo >> 7) & 0xFFu;
                if (e < 0x60u || e > 0x9Fu) { f32 = 1; break; }  // implausible bf16 exponent
            }
        }
        flags[tid] = f32;
    }
    __syncthreads();
    if (tid == 0) {
        int o = 0;
        for (int i = 0; i < 8; i++) o |= flags[i];
        flags[8] = o;   // output dtype via promotion: any f32 input -> f32 out
    }
}

// One block (256 threads) per token: routing scores + argmax + sigmoid gate + LN.
__global__ __launch_bounds__(256) void k_route_ln(
    const void* __restrict__ x,
    const void* __restrict__ cent,
    const void* __restrict__ gamma,
    const void* __restrict__ beta,
    const int* __restrict__ flags,
    __hip_bfloat16* __restrict__ hnorm,
    float* __restrict__ alpha,
    int* __restrict__ cnt,
    int* __restrict__ bucket)
{
    __shared__ float centS[NE * DIM];
    __shared__ float part[4][10];
    __shared__ float bc[3];   // mu, rstd, expert-bits

    const int tid = threadIdx.x;
    const int t = blockIdx.x;
    const int fx = flags[0], fc = flags[1], fg = flags[2], fb = flags[3];

    for (int i = tid; i < NE * DIM; i += 256) centS[i] = ldf(cent, i, fc);

    float xv[4];
    #pragma unroll
    for (int i = 0; i < 4; i++)
        xv[i] = ldf(x, (size_t)t * DIM + tid + 256 * i, fx);

    __syncthreads();

    float s = 0.f, sq = 0.f, c[NE];
    #pragma unroll
    for (int e = 0; e < NE; e++) c[e] = 0.f;

    #pragma unroll
    for (int i = 0; i < 4; i++) {
        const int d = tid + 256 * i;
        const float f = xv[i];
        s += f; sq += f * f;
        #pragma unroll
        for (int e = 0; e < NE; e++)
            c[e] += f * centS[e * DIM + d];
    }

    #pragma unroll
    for (int o = 32; o > 0; o >>= 1) {
        s  += __shfl_xor(s, o);
        sq += __shfl_xor(sq, o);
        #pragma unroll
        for (int e = 0; e < NE; e++) c[e] += __shfl_xor(c[e], o);
    }
    const int wid = tid >> 6, lid = tid & 63;
    if (lid == 0) {
        part[wid][0] = s; part[wid][1] = sq;
        #pragma unroll
        for (int e = 0; e < NE; e++) part[wid][2 + e] = c[e];
    }
    __syncthreads();

    if (tid == 0) {
        float S = 0.f, SQ = 0.f, C[NE];
        #pragma unroll
        for (int e = 0; e < NE; e++) C[e] = 0.f;
        for (int w = 0; w < 4; w++) {
            S += part[w][0]; SQ += part[w][1];
            #pragma unroll
            for (int e = 0; e < NE; e++) C[e] += part[w][2 + e];
        }
        const float mu = S / (float)DIM;
        const float var = SQ / (float)DIM - mu * mu;
        const float rstd = rsqrtf(var + EPSV);
        int be = 0; float bs = C[0];
        #pragma unroll
        for (int e = 1; e < NE; e++)
            if (C[e] > bs) { bs = C[e]; be = e; }   // first-occurrence argmax
        alpha[t] = 1.f / (1.f + expf(-bs));
        const int pos = atomicAdd(&cnt[be], 1);
        bucket[be * BUCKET_STRIDE + pos] = t;
        bc[0] = mu; bc[1] = rstd; bc[2] = __int_as_float(be);
    }
    __syncthreads();

    const float mu = bc[0], rstd = bc[1];
    const int e = __float_as_int(bc[2]);
    #pragma unroll
    for (int i = 0; i < 4; i++) {
        const int d = tid + 256 * i;
        const float g = ldf(gamma, (size_t)e * DIM + d, fg);
        const float b = ldf(beta,  (size_t)e * DIM + d, fb);
        const float h = (xv[i] - mu) * rstd * g + b;
        hnorm[(size_t)t * DIM + d] = __float2bfloat16(h);
    }
}

// Single thread: build tile list (M_TILE=128), pad buckets to multiples of 128.
__global__ void k_plan(const int* __restrict__ cnt, int* __restrict__ bucket,
                       int* __restrict__ tiles, int* __restrict__ numTiles)
{
    if (threadIdx.x == 0 && blockIdx.x == 0) {
        int nt = 0;
        for (int e = 0; e < NE; e++) {
            const int n = cnt[e];
            const int mt = (n + 127) >> 7;
            const int fill = (n > 0) ? bucket[e * BUCKET_STRIDE] : 0;
            for (int i = n; i < mt * 128; i++) bucket[e * BUCKET_STRIDE + i] = fill;
            for (int i = 0; i < mt; i++) tiles[nt++] = (e << 16) | (i * 128);
        }
        *numTiles = nt;
    }
}

// ---------- ff1: h1 = relu(hnorm @ W1_e^T + b1_e), weights in native dtype ----------
// Block: 256 thr (4 waves, 2M x 2N). Tile: M=128 tokens x N=64 ff-cols. nb = FF/64 = 64.
template<int FW>
__device__ __forceinline__ void ff1_core(
    const short* __restrict__ hnorm,
    const void* __restrict__ W1,
    const void* __restrict__ b1, const int fB,
    __hip_bfloat16* __restrict__ h1,
    const int* __restrict__ tiles, const int nt,
    const int* __restrict__ cnt, const int* __restrict__ bucket)
{
    const int bid = blockIdx.x;
    const int tile = bid >> 6;
    if (tile >= nt) return;
    const int nb = bid & 63;
    const int td = tiles[tile];
    const int e = td >> 16;
    const int mbase = td & 0xffff;
    const int ne = cnt[e];

    const int tid = threadIdx.x;
    const int wid = tid >> 6, lane = tid & 63;
    const int wm = wid >> 1, wn = wid & 1;
    const int mr = lane & 15, q = lane >> 4;

    const int m0 = mbase + wm * 64;           // slot base for this wave (64 rows)
    const int n0 = nb * 64 + wn * 32;         // ff-col base for this wave (32 cols)

    // hoist A row pointers (4 M-fragments of 16 token rows)
    const short* Ap[4];
    #pragma unroll
    for (int am = 0; am < 4; am++) {
        const int tok = bucket[e * BUCKET_STRIDE + m0 + am * 16 + mr];
        Ap[am] = hnorm + (size_t)tok * DIM + q * 8;
    }
    // B row element-offsets (2 N-fragments)
    size_t Brow[2];
    #pragma unroll
    for (int an = 0; an < 2; an++)
        Brow[an] = ((size_t)e * FF + n0 + an * 16 + mr) * DIM + q * 8;

    floatx4 acc[4][2];
    #pragma unroll
    for (int am = 0; am < 4; am++)
        #pragma unroll
        for (int an = 0; an < 2; an++) acc[am][an] = (floatx4){0.f, 0.f, 0.f, 0.f};

    #pragma unroll 2
    for (int k = 0; k < DIM; k += 32) {
        short8 a[4], b[2];
        #pragma unroll
        for (int am = 0; am < 4; am++) a[am] = *(const short8*)(Ap[am] + k);
        #pragma unroll
        for (int an = 0; an < 2; an++) b[an] = ldfrag8T<FW>(W1, Brow[an] + k);
        #pragma unroll
        for (int am = 0; am < 4; am++)
            #pragma unroll
            for (int an = 0; an < 2; an++)
                acc[am][an] = __builtin_amdgcn_mfma_f32_16x16x32_bf16(a[am], b[an], acc[am][an], 0, 0, 0);
    }

    #pragma unroll
    for (int am = 0; am < 4; am++) {
        #pragma unroll
        for (int r = 0; r < 4; r++) {
            const int slot = m0 + am * 16 + q * 4 + r;
            if (slot < ne) {
                const int tr = bucket[e * BUCKET_STRIDE + slot];
                #pragma unroll
                for (int an = 0; an < 2; an++) {
                    const int f = n0 + an * 16 + mr;
                    float v = acc[am][an][r] + ldf(b1, (size_t)e * FF + f, fB);
                    v = v > 0.f ? v : 0.f;
                    h1[(size_t)tr * FF + f] = __float2bfloat16(v);
                }
            }
        }
    }
}

__global__ __launch_bounds__(256) void k_ff1(
    const __hip_bfloat16* __restrict__ hnorm,
    const void* __restrict__ W1,
    const void* __restrict__ b1,
    const int* __restrict__ flags,
    __hip_bfloat16* __restrict__ h1,
    const int* __restrict__ tiles,
    const int* __restrict__ numTiles,
    const int* __restrict__ cnt,
    const int* __restrict__ bucket)
{
    const int nt = *numTiles;
    if (flags[4]) ff1_core<1>((const short*)hnorm, W1, b1, flags[5], h1, tiles, nt, cnt, bucket);
    else          ff1_core<0>((const short*)hnorm, W1, b1, flags[5], h1, tiles, nt, cnt, bucket);
}

// ---------- ff2: out = x + alpha * (h1 @ W2_e^T + b2_e) ----------
// Block: 256 thr (4 waves splitting M). Tile: M=128 tokens x N=32 d-cols. nb = DIM/32 = 32.
template<int FW>
__device__ __forceinline__ void ff2_core(
    const short* __restrict__ h1,
    const void* __restrict__ W2,
    const void* __restrict__ b2, const int fB,
    const void* __restrict__ x, const int fx,
    const float* __restrict__ alpha,
    void* __restrict__ out, const int fo,
    const int* __restrict__ tiles, const int nt,
    const int* __restrict__ cnt, const int* __restrict__ bucket)
{
    const int bid = blockIdx.x;
    const int tile = bid >> 5;
    if (tile >= nt) return;
    const int nb = bid & 31;
    const int td = tiles[tile];
    const int e = td >> 16;
    const int mbase = td & 0xffff;
    const int ne = cnt[e];

    const int tid = threadIdx.x;
    const int wid = tid >> 6, lane = tid & 63;
    const int mr = lane & 15, q = lane >> 4;

    const int m0 = mbase + wid * 32;          // wave owns 32 token rows
    const int n0 = nb * 32;                   // 32 d-cols (shared by all 4 waves -> B hits L1)

    const short* Ap[2];
    #pragma unroll
    for (int am = 0; am < 2; am++) {
        const int tok = bucket[e * BUCKET_STRIDE + m0 + am * 16 + mr];
        Ap[am] = h1 + (size_t)tok * FF + q * 8;
    }
    size_t Brow[2];
    #pragma unroll
    for (int an = 0; an < 2; an++)
        Brow[an] = ((size_t)e * DIM + n0 + an * 16 + mr) * FF + q * 8;

    floatx4 acc[2][2];
    #pragma unroll
    for (int am = 0; am < 2; am++)
        #pragma unroll
        for (int an = 0; an < 2; an++) acc[am][an] = (floatx4){0.f, 0.f, 0.f, 0.f};

    #pragma unroll 4
    for (int k = 0; k < FF; k += 32) {
        short8 a[2], b[2];
        #pragma unroll
        for (int am = 0; am < 2; am++) a[am] = *(const short8*)(Ap[am] + k);
        #pragma unroll
        for (int an = 0; an < 2; an++) b[an] = ldfrag8T<FW>(W2, Brow[an] + k);
        #pragma unroll
        for (int am = 0; am < 2; am++)
            #pragma unroll
            for (int an = 0; an < 2; an++)
                acc[am][an] = __builtin_amdgcn_mfma_f32_16x16x32_bf16(a[am], b[an], acc[am][an], 0, 0, 0);
    }

    #pragma unroll
    for (int am = 0; am < 2; am++) {
        #pragma unroll
        for (int r = 0; r < 4; r++) {
            const int slot = m0 + am * 16 + q * 4 + r;
            if (slot < ne) {
                const int tr = bucket[e * BUCKET_STRIDE + slot];
                const float al = alpha[tr];
                #pragma unroll
                for (int an = 0; an < 2; an++) {
                    const int d = n0 + an * 16 + mr;
                    const float xb = ldf(x, (size_t)tr * DIM + d, fx);
                    const float v = xb + al * (acc[am][an][r] + ldf(b2, (size_t)e * DIM + d, fB));
                    stout(out, (size_t)tr * DIM + d, v, fo);
                }
            }
        }
    }
}

__global__ __launch_bounds__(256) void k_ff2(
    const __hip_bfloat16* __restrict__ h1,
    const void* __restrict__ W2,
    const void* __restrict__ b2,
    const void* __restrict__ x,
    const int* __restrict__ flags,
    const float* __restrict__ alpha,
    void* __restrict__ out,
    const int* __restrict__ tiles,
    const int* __restrict__ numTiles,
    const int* __restrict__ cnt,
    const int* __restrict__ bucket)
{
    const int nt = *numTiles;
    if (flags[6]) ff2_core<1>((const short*)h1, W2, b2, flags[7], x, flags[0], alpha, out, flags[8], tiles, nt, cnt, bucket);
    else          ff2_core<0>((const short*)h1, W2, b2, flags[7], x, flags[0], alpha, out, flags[8], tiles, nt, cnt, bucket);
}

extern "C" void kernel_launch(void* const* d_in, const int* in_sizes, int n_in,
                              void* d_out, int out_size, void* d_ws, size_t ws_size,
                              hipStream_t stream) {
    char* ws = (char*)d_ws;
    Ptr8 ptrs;
    for (int i = 0; i < 8; i++) ptrs.p[i] = d_in[i];

    __hip_bfloat16* hnorm = (__hip_bfloat16*)(ws + OFF_HNORM);
    __hip_bfloat16* h1    = (__hip_bfloat16*)(ws + OFF_H1);
    float* alpha          = (float*)(ws + OFF_ALPHA);
    int* cnt              = (int*)(ws + OFF_CNT);
    int* numTiles         = (int*)(ws + OFF_NT);
    int* tiles            = (int*)(ws + OFF_TILES);
    int* bucket           = (int*)(ws + OFF_BUCKET);
    int* flags            = (int*)(ws + OFF_FLAGS);

    k_init<<<1, 64, 0, stream>>>(ptrs, cnt, flags);
    k_route_ln<<<TOK, 256, 0, stream>>>(d_in[0], d_in[1], d_in[2], d_in[3], flags,
                                        hnorm, alpha, cnt, bucket);
    k_plan<<<1, 64, 0, stream>>>(cnt, bucket, tiles, numTiles);
    k_ff1<<<MAXT * 64, 256, 0, stream>>>(hnorm, d_in[4], d_in[5], flags, h1,
                                         tiles, numTiles, cnt, bucket);
    k_ff2<<<MAXT * 32, 256, 0, stream>>>(h1, d_in[6], d_in[7], d_in[0], flags,
                                         alpha, d_out, tiles, numTiles, cnt, bucket);
}

// Round 4
// 521.845 us; speedup vs baseline: 1.0266x; 1.0266x over previous
//
#include <hip/hip_runtime.h>
#include <hip/hip_bf16.h>

// Problem constants: B=1, S=1024, D=1024, F=4096, E=8
#define TOK 1024
#define DIM 1024
#define FF  4096
#define NE  8
#define EPSV 1e-5f
#define BUCKET_STRIDE 1040   // >= max padded bucket (ceil(1024/128)*128 = 1024)
#define MAXT 16              // max tiles of 128: sum ceil(n_e/128) <= 15
#define NKC 4                // split-K factor for ff2
#define KC  (FF / NKC)       // 1024

typedef __attribute__((ext_vector_type(8))) short short8;   // 8 bf16 = 4 VGPRs
typedef __attribute__((ext_vector_type(4))) float floatx4;

// -------- workspace layout (bytes) --------
#define OFF_HNORM  0
#define OFF_H1     (OFF_HNORM + (size_t)TOK*DIM*2)
#define OFF_PART   (OFF_H1 + (size_t)TOK*FF*2)                 // NKC x TOK x DIM f32
#define OFF_ALPHA  (OFF_PART + (size_t)NKC*TOK*DIM*4)
#define OFF_EID    (OFF_ALPHA + TOK*4)
#define OFF_CNT    (OFF_EID + TOK*4)
#define OFF_NT     (OFF_CNT + NE*4)
#define OFF_TILES  (OFF_NT + 4)
#define OFF_BUCKET (OFF_TILES + 64*4)
#define OFF_FLAGS  (OFF_BUCKET + NE*BUCKET_STRIDE*4)   // 9 ints (16 reserved)

struct Ptr8 { const void* p[8]; };

// ---- dual-dtype helpers (flag: 1 = buffer is float32, 0 = bf16) ----
__device__ __forceinline__ float ldf(const void* p, size_t i, int f32) {
    if (f32) return ((const float*)p)[i];
    union { unsigned u; float f; } v;
    v.u = ((unsigned)((const unsigned short*)p)[i]) << 16;
    return v.f;
}

__device__ __forceinline__ short bf16rne(float f) {
    unsigned u = __float_as_uint(f);
    return (short)((u + 0x7FFFu + ((u >> 16) & 1u)) >> 16);
}

// Fragment loader, dtype resolved at COMPILE time (kernel unswitched on flag).
template<int F32>
__device__ __forceinline__ short8 ldfrag8T(const void* p, size_t i) {
    if (F32) {
        const floatx4* fp = (const floatx4*)((const float*)p + i);
        const floatx4 a = fp[0], b = fp[1];
        short8 r;
        #pragma unroll
        for (int j = 0; j < 4; j++) { r[j] = bf16rne(a[j]); r[4 + j] = bf16rne(b[j]); }
        return r;
    } else {
        return *(const short8*)((const short*)p + i);
    }
}

__device__ __forceinline__ void stout(void* p, size_t i, float v, int f32) {
    if (f32) ((float*)p)[i] = v;
    else ((__hip_bfloat16*)p)[i] = __float2bfloat16(v);
}

// Zero cnt + classify each input buffer's dtype by bit-pattern scan.
__global__ void k_init(Ptr8 ptrs, int* __restrict__ cnt, int* __restrict__ flags) {
    const int tid = threadIdx.x;
    if (tid < NE) cnt[tid] = 0;
    if (tid < 8) {
        const unsigned* w = (const unsigned*)ptrs.p[tid];
        int f32 = 0;
        for (int i = 0; i < 64; i++) {
            const unsigned v = w[i];
            if (v == 0x3F800000u) { f32 = 1; break; }   // exact f32 1.0 (e.g. gamma=ones)
            const unsigned lo = v & 0xFFFFu;
            if (lo != 0) {
                const unsigned e = (lo >> 7) & 0xFFu;
                if (e < 0x60u || e > 0x9Fu) { f32 = 1; break; }  // implausible bf16 exponent
            }
        }
        flags[tid] = f32;
    }
    __syncthreads();
    if (tid == 0) {
        int o = 0;
        for (int i = 0; i < 8; i++) o |= flags[i];
        flags[8] = o;   // output dtype via promotion: any f32 input -> f32 out
    }
}

// One block (256 threads) per token: routing scores + argmax + sigmoid gate + LN.
__global__ __launch_bounds__(256) void k_route_ln(
    const void* __restrict__ x,
    const void* __restrict__ cent,
    const void* __restrict__ gamma,
    const void* __restrict__ beta,
    const int* __restrict__ flags,
    __hip_bfloat16* __restrict__ hnorm,
    float* __restrict__ alpha,
    int* __restrict__ eid,
    int* __restrict__ cnt,
    int* __restrict__ bucket)
{
    __shared__ float centS[NE * DIM];
    __shared__ float part[4][10];
    __shared__ float bc[3];   // mu, rstd, expert-bits

    const int tid = threadIdx.x;
    const int t = blockIdx.x;
    const int fx = flags[0], fc = flags[1], fg = flags[2], fb = flags[3];

    for (int i = tid; i < NE * DIM; i += 256) centS[i] = ldf(cent, i, fc);

    float xv[4];
    #pragma unroll
    for (int i = 0; i < 4; i++)
        xv[i] = ldf(x, (size_t)t * DIM + tid + 256 * i, fx);

    __syncthreads();

    float s = 0.f, sq = 0.f, c[NE];
    #pragma unroll
    for (int e = 0; e < NE; e++) c[e] = 0.f;

    #pragma unroll
    for (int i = 0; i < 4; i++) {
        const int d = tid + 256 * i;
        const float f = xv[i];
        s += f; sq += f * f;
        #pragma unroll
        for (int e = 0; e < NE; e++)
            c[e] += f * centS[e * DIM + d];
    }

    #pragma unroll
    for (int o = 32; o > 0; o >>= 1) {
        s  += __shfl_xor(s, o);
        sq += __shfl_xor(sq, o);
        #pragma unroll
        for (int e = 0; e < NE; e++) c[e] += __shfl_xor(c[e], o);
    }
    const int wid = tid >> 6, lid = tid & 63;
    if (lid == 0) {
        part[wid][0] = s; part[wid][1] = sq;
        #pragma unroll
        for (int e = 0; e < NE; e++) part[wid][2 + e] = c[e];
    }
    __syncthreads();

    if (tid == 0) {
        float S = 0.f, SQ = 0.f, C[NE];
        #pragma unroll
        for (int e = 0; e < NE; e++) C[e] = 0.f;
        for (int w = 0; w < 4; w++) {
            S += part[w][0]; SQ += part[w][1];
            #pragma unroll
            for (int e = 0; e < NE; e++) C[e] += part[w][2 + e];
        }
        const float mu = S / (float)DIM;
        const float var = SQ / (float)DIM - mu * mu;
        const float rstd = rsqrtf(var + EPSV);
        int be = 0; float bs = C[0];
        #pragma unroll
        for (int e = 1; e < NE; e++)
            if (C[e] > bs) { bs = C[e]; be = e; }   // first-occurrence argmax
        alpha[t] = 1.f / (1.f + expf(-bs));
        eid[t] = be;
        const int pos = atomicAdd(&cnt[be], 1);
        bucket[be * BUCKET_STRIDE + pos] = t;
        bc[0] = mu; bc[1] = rstd; bc[2] = __int_as_float(be);
    }
    __syncthreads();

    const float mu = bc[0], rstd = bc[1];
    const int e = __float_as_int(bc[2]);
    #pragma unroll
    for (int i = 0; i < 4; i++) {
        const int d = tid + 256 * i;
        const float g = ldf(gamma, (size_t)e * DIM + d, fg);
        const float b = ldf(beta,  (size_t)e * DIM + d, fb);
        const float h = (xv[i] - mu) * rstd * g + b;
        hnorm[(size_t)t * DIM + d] = __float2bfloat16(h);
    }
}

// Single thread: build tile list (M_TILE=128), pad buckets to multiples of 128.
__global__ void k_plan(const int* __restrict__ cnt, int* __restrict__ bucket,
                       int* __restrict__ tiles, int* __restrict__ numTiles)
{
    if (threadIdx.x == 0 && blockIdx.x == 0) {
        int nt = 0;
        for (int e = 0; e < NE; e++) {
            const int n = cnt[e];
            const int mt = (n + 127) >> 7;
            const int fill = (n > 0) ? bucket[e * BUCKET_STRIDE] : 0;
            for (int i = n; i < mt * 128; i++) bucket[e * BUCKET_STRIDE + i] = fill;
            for (int i = 0; i < mt; i++) tiles[nt++] = (e << 16) | (i * 128);
        }
        *numTiles = nt;
    }
}

// ---------- ff1: h1 = relu(hnorm @ W1_e^T + b1_e), weights in native dtype ----------
// Block: 256 thr (4 waves splitting M). Tile: M=128 tokens x N=32 ff-cols. nb = FF/32 = 128.
template<int FW>
__device__ __forceinline__ void ff1_core(
    const short* __restrict__ hnorm,
    const void* __restrict__ W1,
    const void* __restrict__ b1, const int fB,
    __hip_bfloat16* __restrict__ h1,
    const int* __restrict__ tiles, const int nt,
    const int* __restrict__ cnt, const int* __restrict__ bucket)
{
    const int bid = blockIdx.x;
    const int tile = bid >> 7;
    if (tile >= nt) return;
    const int nb = bid & 127;
    const int td = tiles[tile];
    const int e = td >> 16;
    const int mbase = td & 0xffff;
    const int ne = cnt[e];

    const int tid = threadIdx.x;
    const int wid = tid >> 6, lane = tid & 63;
    const int mr = lane & 15, q = lane >> 4;

    const int m0 = mbase + wid * 32;          // wave owns 32 token rows
    const int n0 = nb * 32;                   // 32 ff-cols shared by all 4 waves (L1 reuse)

    const short* Ap[2];
    #pragma unroll
    for (int am = 0; am < 2; am++) {
        const int tok = bucket[e * BUCKET_STRIDE + m0 + am * 16 + mr];
        Ap[am] = hnorm + (size_t)tok * DIM + q * 8;
    }
    size_t Brow[2];
    #pragma unroll
    for (int an = 0; an < 2; an++)
        Brow[an] = ((size_t)e * FF + n0 + an * 16 + mr) * DIM + q * 8;

    floatx4 acc[2][2];
    #pragma unroll
    for (int am = 0; am < 2; am++)
        #pragma unroll
        for (int an = 0; an < 2; an++) acc[am][an] = (floatx4){0.f, 0.f, 0.f, 0.f};

    #pragma unroll 4
    for (int k = 0; k < DIM; k += 32) {
        short8 a[2], b[2];
        #pragma unroll
        for (int am = 0; am < 2; am++) a[am] = *(const short8*)(Ap[am] + k);
        #pragma unroll
        for (int an = 0; an < 2; an++) b[an] = ldfrag8T<FW>(W1, Brow[an] + k);
        #pragma unroll
        for (int am = 0; am < 2; am++)
            #pragma unroll
            for (int an = 0; an < 2; an++)
                acc[am][an] = __builtin_amdgcn_mfma_f32_16x16x32_bf16(a[am], b[an], acc[am][an], 0, 0, 0);
    }

    #pragma unroll
    for (int am = 0; am < 2; am++) {
        #pragma unroll
        for (int r = 0; r < 4; r++) {
            const int slot = m0 + am * 16 + q * 4 + r;
            if (slot < ne) {
                const int tr = bucket[e * BUCKET_STRIDE + slot];
                #pragma unroll
                for (int an = 0; an < 2; an++) {
                    const int f = n0 + an * 16 + mr;
                    float v = acc[am][an][r] + ldf(b1, (size_t)e * FF + f, fB);
                    v = v > 0.f ? v : 0.f;
                    h1[(size_t)tr * FF + f] = __float2bfloat16(v);
                }
            }
        }
    }
}

__global__ __launch_bounds__(256) void k_ff1(
    const __hip_bfloat16* __restrict__ hnorm,
    const void* __restrict__ W1,
    const void* __restrict__ b1,
    const int* __restrict__ flags,
    __hip_bfloat16* __restrict__ h1,
    const int* __restrict__ tiles,
    const int* __restrict__ numTiles,
    const int* __restrict__ cnt,
    const int* __restrict__ bucket)
{
    const int nt = *numTiles;
    if (flags[4]) ff1_core<1>((const short*)hnorm, W1, b1, flags[5], h1, tiles, nt, cnt, bucket);
    else          ff1_core<0>((const short*)hnorm, W1, b1, flags[5], h1, tiles, nt, cnt, bucket);
}

// ---------- ff2 split-K: part[kc] = h1 @ W2_e^T (partial over K-chunk) ----------
// Block: 256 thr (4 waves splitting M). Tile: M=128 x N=32 d-cols x K=1024 chunk.
// grid decomposition: tile = bid>>7, nb = (bid>>2)&31, kc = bid&3.
template<int FW>
__device__ __forceinline__ void ff2_core(
    const short* __restrict__ h1,
    const void* __restrict__ W2,
    float* __restrict__ part,
    const int* __restrict__ tiles, const int nt,
    const int* __restrict__ cnt, const int* __restrict__ bucket)
{
    const int bid = blockIdx.x;
    const int tile = bid >> 7;
    if (tile >= nt) return;
    const int nb = (bid >> 2) & 31;
    const int kc = bid & 3;
    const int td = tiles[tile];
    const int e = td >> 16;
    const int mbase = td & 0xffff;
    const int ne = cnt[e];

    const int tid = threadIdx.x;
    const int wid = tid >> 6, lane = tid & 63;
    const int mr = lane & 15, q = lane >> 4;

    const int m0 = mbase + wid * 32;          // wave owns 32 token rows
    const int n0 = nb * 32;                   // 32 d-cols shared by all 4 waves
    const int kbase = kc * KC;

    const short* Ap[2];
    #pragma unroll
    for (int am = 0; am < 2; am++) {
        const int tok = bucket[e * BUCKET_STRIDE + m0 + am * 16 + mr];
        Ap[am] = h1 + (size_t)tok * FF + kbase + q * 8;
    }
    size_t Brow[2];
    #pragma unroll
    for (int an = 0; an < 2; an++)
        Brow[an] = ((size_t)e * DIM + n0 + an * 16 + mr) * FF + kbase + q * 8;

    floatx4 acc[2][2];
    #pragma unroll
    for (int am = 0; am < 2; am++)
        #pragma unroll
        for (int an = 0; an < 2; an++) acc[am][an] = (floatx4){0.f, 0.f, 0.f, 0.f};

    #pragma unroll 4
    for (int k = 0; k < KC; k += 32) {
        short8 a[2], b[2];
        #pragma unroll
        for (int am = 0; am < 2; am++) a[am] = *(const short8*)(Ap[am] + k);
        #pragma unroll
        for (int an = 0; an < 2; an++) b[an] = ldfrag8T<FW>(W2, Brow[an] + k);
        #pragma unroll
        for (int am = 0; am < 2; am++)
            #pragma unroll
            for (int an = 0; an < 2; an++)
                acc[am][an] = __builtin_amdgcn_mfma_f32_16x16x32_bf16(a[am], b[an], acc[am][an], 0, 0, 0);
    }

    float* pk = part + (size_t)kc * TOK * DIM;
    #pragma unroll
    for (int am = 0; am < 2; am++) {
        #pragma unroll
        for (int r = 0; r < 4; r++) {
            const int slot = m0 + am * 16 + q * 4 + r;
            if (slot < ne) {
                const int tr = bucket[e * BUCKET_STRIDE + slot];
                #pragma unroll
                for (int an = 0; an < 2; an++) {
                    const int d = n0 + an * 16 + mr;
                    pk[(size_t)tr * DIM + d] = acc[am][an][r];
                }
            }
        }
    }
}

__global__ __launch_bounds__(256) void k_ff2(
    const __hip_bfloat16* __restrict__ h1,
    const void* __restrict__ W2,
    const int* __restrict__ flags,
    float* __restrict__ part,
    const int* __restrict__ tiles,
    const int* __restrict__ numTiles,
    const int* __restrict__ cnt,
    const int* __restrict__ bucket)
{
    const int nt = *numTiles;
    if (flags[6]) ff2_core<1>((const short*)h1, W2, part, tiles, nt, cnt, bucket);
    else          ff2_core<0>((const short*)h1, W2, part, tiles, nt, cnt, bucket);
}

// ---------- epilogue: out = x + alpha * (sum_kc part[kc] + b2_e) ----------
// One block per token; each thread handles 4 consecutive d via float4 partial loads.
__global__ __launch_bounds__(256) void k_out(
    const float* __restrict__ part,
    const void* __restrict__ b2,
    const void* __restrict__ x,
    const int* __restrict__ flags,
    const float* __restrict__ alpha,
    const int* __restrict__ eid,
    void* __restrict__ out)
{
    const int t = blockIdx.x;
    const int tid = threadIdx.x;
    const int fB = flags[7], fx = flags[0], fo = flags[8];
    const int e = eid[t];
    const float al = alpha[t];
    const int d0 = tid * 4;

    floatx4 s = (floatx4){0.f, 0.f, 0.f, 0.f};
    #pragma unroll
    for (int kc = 0; kc < NKC; kc++) {
        const floatx4 p = *(const floatx4*)(part + (size_t)kc * TOK * DIM + (size_t)t * DIM + d0);
        s[0] += p[0]; s[1] += p[1]; s[2] += p[2]; s[3] += p[3];
    }
    #pragma unroll
    for (int j = 0; j < 4; j++) {
        const int d = d0 + j;
        const float xb = ldf(x, (size_t)t * DIM + d, fx);
        const float v = xb + al * (s[j] + ldf(b2, (size_t)e * DIM + d, fB));
        stout(out, (size_t)t * DIM + d, v, fo);
    }
}

extern "C" void kernel_launch(void* const* d_in, const int* in_sizes, int n_in,
                              void* d_out, int out_size, void* d_ws, size_t ws_size,
                              hipStream_t stream) {
    char* ws = (char*)d_ws;
    Ptr8 ptrs;
    for (int i = 0; i < 8; i++) ptrs.p[i] = d_in[i];

    __hip_bfloat16* hnorm = (__hip_bfloat16*)(ws + OFF_HNORM);
    __hip_bfloat16* h1    = (__hip_bfloat16*)(ws + OFF_H1);
    float* part           = (float*)(ws + OFF_PART);
    float* alpha          = (float*)(ws + OFF_ALPHA);
    int* eid              = (int*)(ws + OFF_EID);
    int* cnt              = (int*)(ws + OFF_CNT);
    int* numTiles         = (int*)(ws + OFF_NT);
    int* tiles            = (int*)(ws + OFF_TILES);
    int* bucket           = (int*)(ws + OFF_BUCKET);
    int* flags            = (int*)(ws + OFF_FLAGS);

    k_init<<<1, 64, 0, stream>>>(ptrs, cnt, flags);
    k_route_ln<<<TOK, 256, 0, stream>>>(d_in[0], d_in[1], d_in[2], d_in[3], flags,
                                        hnorm, alpha, eid, cnt, bucket);
    k_plan<<<1, 64, 0, stream>>>(cnt, bucket, tiles, numTiles);
    k_ff1<<<MAXT * 128, 256, 0, stream>>>(hnorm, d_in[4], d_in[5], flags, h1,
                                          tiles, numTiles, cnt, bucket);
    k_ff2<<<MAXT * 128, 256, 0, stream>>>(h1, d_in[6], flags, part,
                                          tiles, numTiles, cnt, bucket);
    k_out<<<TOK, 256, 0, stream>>>(part, d_in[7], d_in[0], flags, alpha, eid, d_out);
}

// Round 5
// 382.394 us; speedup vs baseline: 1.4010x; 1.3647x over previous
//
#include <hip/hip_runtime.h>
#include <hip/hip_bf16.h>

// Problem constants: B=1, S=1024, D=1024, F=4096, E=8
#define TOK 1024
#define DIM 1024
#define FF  4096
#define NE  8
#define EPSV 1e-5f
#define BUCKET_STRIDE 1040   // >= max padded bucket (ceil(1024/128)*128 = 1024)
#define MAXT 16              // max tiles of 128: sum ceil(n_e/128) <= 15
#define NKC 4                // split-K factor for ff2
#define KC  (FF / NKC)       // 1024

typedef __attribute__((ext_vector_type(8))) short short8;   // 8 bf16 = 4 VGPRs
typedef __attribute__((ext_vector_type(4))) float floatx4;

// -------- workspace layout (bytes) --------
#define OFF_HNORM  0
#define OFF_H1     (OFF_HNORM + (size_t)TOK*DIM*2)
#define OFF_PART   (OFF_H1 + (size_t)TOK*FF*2)                 // NKC x TOK x DIM f32
#define OFF_ALPHA  (OFF_PART + (size_t)NKC*TOK*DIM*4)
#define OFF_EID    (OFF_ALPHA + TOK*4)
#define OFF_CNT    (OFF_EID + TOK*4)
#define OFF_NT     (OFF_CNT + NE*4)
#define OFF_TILES  (OFF_NT + 4)
#define OFF_BUCKET (OFF_TILES + 64*4)
#define OFF_FLAGS  (OFF_BUCKET + NE*BUCKET_STRIDE*4)   // 9 ints (16 reserved)

struct Ptr8 { const void* p[8]; };

// async global->LDS, 16B per lane. LDS dest is wave-uniform base + lane*16.
__device__ __forceinline__ void gload16(const void* g, void* l) {
    __builtin_amdgcn_global_load_lds(
        (const __attribute__((address_space(1))) void*)g,
        (__attribute__((address_space(3))) void*)l, 16, 0, 0);
}

// ---- dual-dtype helpers (flag: 1 = buffer is float32, 0 = bf16) ----
__device__ __forceinline__ float ldf(const void* p, size_t i, int f32) {
    if (f32) return ((const float*)p)[i];
    union { unsigned u; float f; } v;
    v.u = ((unsigned)((const unsigned short*)p)[i]) << 16;
    return v.f;
}

__device__ __forceinline__ short bf16rne(float f) {
    unsigned u = __float_as_uint(f);
    return (short)((u + 0x7FFFu + ((u >> 16) & 1u)) >> 16);
}

__device__ __forceinline__ void stout(void* p, size_t i, float v, int f32) {
    if (f32) ((float*)p)[i] = v;
    else ((__hip_bfloat16*)p)[i] = __float2bfloat16(v);
}

// Zero cnt + classify each input buffer's dtype by bit-pattern scan.
__global__ void k_init(Ptr8 ptrs, int* __restrict__ cnt, int* __restrict__ flags) {
    const int tid = threadIdx.x;
    if (tid < NE) cnt[tid] = 0;
    if (tid < 8) {
        const unsigned* w = (const unsigned*)ptrs.p[tid];
        int f32 = 0;
        for (int i = 0; i < 64; i++) {
            const unsigned v = w[i];
            if (v == 0x3F800000u) { f32 = 1; break; }   // exact f32 1.0 (e.g. gamma=ones)
            const unsigned lo = v & 0xFFFFu;
            if (lo != 0) {
                const unsigned e = (lo >> 7) & 0xFFu;
                if (e < 0x60u || e > 0x9Fu) { f32 = 1; break; }  // implausible bf16 exponent
            }
        }
        flags[tid] = f32;
    }
    __syncthreads();
    if (tid == 0) {
        int o = 0;
        for (int i = 0; i < 8; i++) o |= flags[i];
        flags[8] = o;   // output dtype via promotion: any f32 input -> f32 out
    }
}

// One block (256 threads) per token: routing scores + argmax + sigmoid gate + LN.
__global__ __launch_bounds__(256) void k_route_ln(
    const void* __restrict__ x,
    const void* __restrict__ cent,
    const void* __restrict__ gamma,
    const void* __restrict__ beta,
    const int* __restrict__ flags,
    __hip_bfloat16* __restrict__ hnorm,
    float* __restrict__ alpha,
    int* __restrict__ eid,
    int* __restrict__ cnt,
    int* __restrict__ bucket)
{
    __shared__ float centS[NE * DIM];
    __shared__ float part[4][10];
    __shared__ float bc[3];   // mu, rstd, expert-bits

    const int tid = threadIdx.x;
    const int t = blockIdx.x;
    const int fx = flags[0], fc = flags[1], fg = flags[2], fb = flags[3];

    for (int i = tid; i < NE * DIM; i += 256) centS[i] = ldf(cent, i, fc);

    float xv[4];
    #pragma unroll
    for (int i = 0; i < 4; i++)
        xv[i] = ldf(x, (size_t)t * DIM + tid + 256 * i, fx);

    __syncthreads();

    float s = 0.f, sq = 0.f, c[NE];
    #pragma unroll
    for (int e = 0; e < NE; e++) c[e] = 0.f;

    #pragma unroll
    for (int i = 0; i < 4; i++) {
        const int d = tid + 256 * i;
        const float f = xv[i];
        s += f; sq += f * f;
        #pragma unroll
        for (int e = 0; e < NE; e++)
            c[e] += f * centS[e * DIM + d];
    }

    #pragma unroll
    for (int o = 32; o > 0; o >>= 1) {
        s  += __shfl_xor(s, o);
        sq += __shfl_xor(sq, o);
        #pragma unroll
        for (int e = 0; e < NE; e++) c[e] += __shfl_xor(c[e], o);
    }
    const int wid = tid >> 6, lid = tid & 63;
    if (lid == 0) {
        part[wid][0] = s; part[wid][1] = sq;
        #pragma unroll
        for (int e = 0; e < NE; e++) part[wid][2 + e] = c[e];
    }
    __syncthreads();

    if (tid == 0) {
        float S = 0.f, SQ = 0.f, C[NE];
        #pragma unroll
        for (int e = 0; e < NE; e++) C[e] = 0.f;
        for (int w = 0; w < 4; w++) {
            S += part[w][0]; SQ += part[w][1];
            #pragma unroll
            for (int e = 0; e < NE; e++) C[e] += part[w][2 + e];
        }
        const float mu = S / (float)DIM;
        const float var = SQ / (float)DIM - mu * mu;
        const float rstd = rsqrtf(var + EPSV);
        int be = 0; float bs = C[0];
        #pragma unroll
        for (int e = 1; e < NE; e++)
            if (C[e] > bs) { bs = C[e]; be = e; }   // first-occurrence argmax
        alpha[t] = 1.f / (1.f + expf(-bs));
        eid[t] = be;
        const int pos = atomicAdd(&cnt[be], 1);
        bucket[be * BUCKET_STRIDE + pos] = t;
        bc[0] = mu; bc[1] = rstd; bc[2] = __int_as_float(be);
    }
    __syncthreads();

    const float mu = bc[0], rstd = bc[1];
    const int e = __float_as_int(bc[2]);
    #pragma unroll
    for (int i = 0; i < 4; i++) {
        const int d = tid + 256 * i;
        const float g = ldf(gamma, (size_t)e * DIM + d, fg);
        const float b = ldf(beta,  (size_t)e * DIM + d, fb);
        const float h = (xv[i] - mu) * rstd * g + b;
        hnorm[(size_t)t * DIM + d] = __float2bfloat16(h);
    }
}

// Single thread: build tile list (M_TILE=128), pad buckets to multiples of 128.
__global__ void k_plan(const int* __restrict__ cnt, int* __restrict__ bucket,
                       int* __restrict__ tiles, int* __restrict__ numTiles)
{
    if (threadIdx.x == 0 && blockIdx.x == 0) {
        int nt = 0;
        for (int e = 0; e < NE; e++) {
            const int n = cnt[e];
            const int mt = (n + 127) >> 7;
            const int fill = (n > 0) ? bucket[e * BUCKET_STRIDE] : 0;
            for (int i = n; i < mt * 128; i++) bucket[e * BUCKET_STRIDE + i] = fill;
            for (int i = 0; i < mt; i++) tiles[nt++] = (e << 16) | (i * 128);
        }
        *numTiles = nt;
    }
}

// ---------- LDS weight staging (both GEMMs) ----------
// B-tile: 64 rows (output cols) x BK=128 K-elements, double-buffered.
// FW=1: f32 rows = 512B (32 x16B slots); FW=0: bf16 rows = 256B (16 slots).
// XOR swizzle: LDS physical slot p of row r holds logical slot p ^ (r&15).
// gload_lds writes linearly, so the SOURCE address carries the swizzle.
template<int FW>
__device__ __forceinline__ void stageB(const char* W, char* ldsbuf,
                                       int wid, int lane,
                                       long rowbase, long rowlen, int kbase)
{
    if (FW) {
        #pragma unroll
        for (int i = 0; i < 8; i++) {
            const int chunk = wid * 8 + i;            // 0..31, 1KB each
            const int row = chunk * 2 + (lane >> 5);  // 0..63
            const int p = lane & 31;
            const int col = (p ^ (row & 15)) << 2;    // f32 col within tile
            const char* src = W + ((rowbase + row) * rowlen + kbase + col) * 4;
            gload16(src, ldsbuf + chunk * 1024);
        }
    } else {
        #pragma unroll
        for (int i = 0; i < 4; i++) {
            const int chunk = wid * 4 + i;            // 0..15
            const int row = chunk * 4 + (lane >> 4);  // 0..63
            const int p = lane & 15;
            const int col = (p ^ (row & 15)) << 3;    // bf16 col within tile
            const char* src = W + ((rowbase + row) * rowlen + kbase + col) * 2;
            gload16(src, ldsbuf + chunk * 1024);
        }
    }
}

// Read one MFMA B-fragment (8 bf16, K-cols ks*32 + q*8 .. +8) for tile row `row`.
template<int FW>
__device__ __forceinline__ short8 ldB(const char* ldsbuf, int row, int ks, int q) {
    if (FW) {
        const int s0 = ks * 8 + q * 2;
        const floatx4 f0 = *(const floatx4*)(ldsbuf + row * 512 + (((s0    ) ^ (row & 15)) << 4));
        const floatx4 f1 = *(const floatx4*)(ldsbuf + row * 512 + (((s0 + 1) ^ (row & 15)) << 4));
        short8 r;
        #pragma unroll
        for (int j = 0; j < 4; j++) { r[j] = bf16rne(f0[j]); r[4 + j] = bf16rne(f1[j]); }
        return r;
    } else {
        const int s = ks * 4 + q;
        return *(const short8*)(ldsbuf + row * 256 + ((s ^ (row & 15)) << 4));
    }
}

// ---------- ff1: h1 = relu(hnorm @ W1_e^T + b1_e) ----------
// Block: 256 thr (4 waves splitting M). Tile: M=128 x N=64, K=1024 in 8 chunks of 128.
template<int FW>
__device__ __forceinline__ void ff1_core(
    const short* __restrict__ hnorm,
    const void* __restrict__ W1,
    const void* __restrict__ b1, const int fB,
    __hip_bfloat16* __restrict__ h1,
    const int* __restrict__ tiles, const int nt,
    const int* __restrict__ cnt, const int* __restrict__ bucket,
    char (*ldsB)[32768])
{
    const int bid = blockIdx.x;
    const int tile = bid >> 6;
    if (tile >= nt) return;
    const int nb = bid & 63;
    const int td = tiles[tile];
    const int e = td >> 16;
    const int mbase = td & 0xffff;
    const int ne = cnt[e];

    const int tid = threadIdx.x;
    const int wid = tid >> 6, lane = tid & 63;
    const int mr = lane & 15, q = lane >> 4;

    const int m0 = mbase + wid * 32;
    const int n0 = nb * 64;

    const short* Ap[2];
    #pragma unroll
    for (int am = 0; am < 2; am++) {
        const int tok = bucket[e * BUCKET_STRIDE + m0 + am * 16 + mr];
        Ap[am] = hnorm + (size_t)tok * DIM + q * 8;
    }

    floatx4 acc[2][4];
    #pragma unroll
    for (int am = 0; am < 2; am++)
        #pragma unroll
        for (int an = 0; an < 4; an++) acc[am][an] = (floatx4){0.f, 0.f, 0.f, 0.f};

    const long rowbase = (long)e * FF + n0;
    stageB<FW>((const char*)W1, ldsB[0], wid, lane, rowbase, DIM, 0);
    __syncthreads();

    int cur = 0;
    for (int kt = 0; kt < 8; kt++) {
        // A-loads first (so compiler A-waits don't drain the prefetch behind them)
        short8 Areg[4][2];
        #pragma unroll
        for (int ks = 0; ks < 4; ks++)
            #pragma unroll
            for (int am = 0; am < 2; am++)
                Areg[ks][am] = *(const short8*)(Ap[am] + kt * 128 + ks * 32);

        if (kt + 1 < 8)
            stageB<FW>((const char*)W1, ldsB[cur ^ 1], wid, lane, rowbase, DIM, (kt + 1) * 128);

        const char* lb = ldsB[cur];
        #pragma unroll
        for (int ks = 0; ks < 4; ks++) {
            short8 b[4];
            #pragma unroll
            for (int an = 0; an < 4; an++) b[an] = ldB<FW>(lb, an * 16 + mr, ks, q);
            #pragma unroll
            for (int am = 0; am < 2; am++)
                #pragma unroll
                for (int an = 0; an < 4; an++)
                    acc[am][an] = __builtin_amdgcn_mfma_f32_16x16x32_bf16(Areg[ks][am], b[an], acc[am][an], 0, 0, 0);
        }
        __syncthreads();   // vmcnt(0) drain overlapped by the compute phase above
        cur ^= 1;
    }

    #pragma unroll
    for (int am = 0; am < 2; am++) {
        #pragma unroll
        for (int r = 0; r < 4; r++) {
            const int slot = m0 + am * 16 + q * 4 + r;
            if (slot < ne) {
                const int tr = bucket[e * BUCKET_STRIDE + slot];
                #pragma unroll
                for (int an = 0; an < 4; an++) {
                    const int f = n0 + an * 16 + mr;
                    float v = acc[am][an][r] + ldf(b1, (size_t)e * FF + f, fB);
                    v = v > 0.f ? v : 0.f;
                    h1[(size_t)tr * FF + f] = __float2bfloat16(v);
                }
            }
        }
    }
}

__global__ __launch_bounds__(256) void k_ff1(
    const __hip_bfloat16* __restrict__ hnorm,
    const void* __restrict__ W1,
    const void* __restrict__ b1,
    const int* __restrict__ flags,
    __hip_bfloat16* __restrict__ h1,
    const int* __restrict__ tiles,
    const int* __restrict__ numTiles,
    const int* __restrict__ cnt,
    const int* __restrict__ bucket)
{
    __shared__ char ldsB[2][32768];
    const int nt = *numTiles;
    if (flags[4]) ff1_core<1>((const short*)hnorm, W1, b1, flags[5], h1, tiles, nt, cnt, bucket, ldsB);
    else          ff1_core<0>((const short*)hnorm, W1, b1, flags[5], h1, tiles, nt, cnt, bucket, ldsB);
}

// ---------- ff2 split-K: part[kc] = h1 @ W2_e^T over K-chunk kc ----------
// Block: 256 thr. Tile: M=128 x N=64 x K=1024 chunk (8 sub-tiles of 128).
// grid: tile = bid>>6; nb = (bid>>2)&15; kc = bid&3.
template<int FW>
__device__ __forceinline__ void ff2_core(
    const short* __restrict__ h1,
    const void* __restrict__ W2,
    float* __restrict__ part,
    const int* __restrict__ tiles, const int nt,
    const int* __restrict__ cnt, const int* __restrict__ bucket,
    char (*ldsB)[32768])
{
    const int bid = blockIdx.x;
    const int tile = bid >> 6;
    if (tile >= nt) return;
    const int nb = (bid >> 2) & 15;
    const int kc = bid & 3;
    const int td = tiles[tile];
    const int e = td >> 16;
    const int mbase = td & 0xffff;
    const int ne = cnt[e];

    const int tid = threadIdx.x;
    const int wid = tid >> 6, lane = tid & 63;
    const int mr = lane & 15, q = lane >> 4;

    const int m0 = mbase + wid * 32;
    const int n0 = nb * 64;
    const int kbase = kc * KC;

    const short* Ap[2];
    #pragma unroll
    for (int am = 0; am < 2; am++) {
        const int tok = bucket[e * BUCKET_STRIDE + m0 + am * 16 + mr];
        Ap[am] = h1 + (size_t)tok * FF + kbase + q * 8;
    }

    floatx4 acc[2][4];
    #pragma unroll
    for (int am = 0; am < 2; am++)
        #pragma unroll
        for (int an = 0; an < 4; an++) acc[am][an] = (floatx4){0.f, 0.f, 0.f, 0.f};

    const long rowbase = (long)e * DIM + n0;
    stageB<FW>((const char*)W2, ldsB[0], wid, lane, rowbase, FF, kbase);
    __syncthreads();

    int cur = 0;
    for (int kt = 0; kt < 8; kt++) {
        short8 Areg[4][2];
        #pragma unroll
        for (int ks = 0; ks < 4; ks++)
            #pragma unroll
            for (int am = 0; am < 2; am++)
                Areg[ks][am] = *(const short8*)(Ap[am] + kt * 128 + ks * 32);

        if (kt + 1 < 8)
            stageB<FW>((const char*)W2, ldsB[cur ^ 1], wid, lane, rowbase, FF, kbase + (kt + 1) * 128);

        const char* lb = ldsB[cur];
        #pragma unroll
        for (int ks = 0; ks < 4; ks++) {
            short8 b[4];
            #pragma unroll
            for (int an = 0; an < 4; an++) b[an] = ldB<FW>(lb, an * 16 + mr, ks, q);
            #pragma unroll
            for (int am = 0; am < 2; am++)
                #pragma unroll
                for (int an = 0; an < 4; an++)
                    acc[am][an] = __builtin_amdgcn_mfma_f32_16x16x32_bf16(Areg[ks][am], b[an], acc[am][an], 0, 0, 0);
        }
        __syncthreads();
        cur ^= 1;
    }

    float* pk = part + (size_t)kc * TOK * DIM;
    #pragma unroll
    for (int am = 0; am < 2; am++) {
        #pragma unroll
        for (int r = 0; r < 4; r++) {
            const int slot = m0 + am * 16 + q * 4 + r;
            if (slot < ne) {
                const int tr = bucket[e * BUCKET_STRIDE + slot];
                #pragma unroll
                for (int an = 0; an < 4; an++) {
                    const int d = n0 + an * 16 + mr;
                    pk[(size_t)tr * DIM + d] = acc[am][an][r];
                }
            }
        }
    }
}

__global__ __launch_bounds__(256) void k_ff2(
    const __hip_bfloat16* __restrict__ h1,
    const void* __restrict__ W2,
    const int* __restrict__ flags,
    float* __restrict__ part,
    const int* __restrict__ tiles,
    const int* __restrict__ numTiles,
    const int* __restrict__ cnt,
    const int* __restrict__ bucket)
{
    __shared__ char ldsB[2][32768];
    const int nt = *numTiles;
    if (flags[6]) ff2_core<1>((const short*)h1, W2, part, tiles, nt, cnt, bucket, ldsB);
    else          ff2_core<0>((const short*)h1, W2, part, tiles, nt, cnt, bucket, ldsB);
}

// ---------- epilogue: out = x + alpha * (sum_kc part[kc] + b2_e) ----------
__global__ __launch_bounds__(256) void k_out(
    const float* __restrict__ part,
    const void* __restrict__ b2,
    const void* __restrict__ x,
    const int* __restrict__ flags,
    const float* __restrict__ alpha,
    const int* __restrict__ eid,
    void* __restrict__ out)
{
    const int t = blockIdx.x;
    const int tid = threadIdx.x;
    const int fB = flags[7], fx = flags[0], fo = flags[8];
    const int e = eid[t];
    const float al = alpha[t];
    const int d0 = tid * 4;

    floatx4 s = (floatx4){0.f, 0.f, 0.f, 0.f};
    #pragma unroll
    for (int kc = 0; kc < NKC; kc++) {
        const floatx4 p = *(const floatx4*)(part + (size_t)kc * TOK * DIM + (size_t)t * DIM + d0);
        s[0] += p[0]; s[1] += p[1]; s[2] += p[2]; s[3] += p[3];
    }
    #pragma unroll
    for (int j = 0; j < 4; j++) {
        const int d = d0 + j;
        const float xb = ldf(x, (size_t)t * DIM + d, fx);
        const float v = xb + al * (s[j] + ldf(b2, (size_t)e * DIM + d, fB));
        stout(out, (size_t)t * DIM + d, v, fo);
    }
}

extern "C" void kernel_launch(void* const* d_in, const int* in_sizes, int n_in,
                              void* d_out, int out_size, void* d_ws, size_t ws_size,
                              hipStream_t stream) {
    char* ws = (char*)d_ws;
    Ptr8 ptrs;
    for (int i = 0; i < 8; i++) ptrs.p[i] = d_in[i];

    __hip_bfloat16* hnorm = (__hip_bfloat16*)(ws + OFF_HNORM);
    __hip_bfloat16* h1    = (__hip_bfloat16*)(ws + OFF_H1);
    float* part           = (float*)(ws + OFF_PART);
    float* alpha          = (float*)(ws + OFF_ALPHA);
    int* eid              = (int*)(ws + OFF_EID);
    int* cnt              = (int*)(ws + OFF_CNT);
    int* numTiles         = (int*)(ws + OFF_NT);
    int* tiles            = (int*)(ws + OFF_TILES);
    int* bucket           = (int*)(ws + OFF_BUCKET);
    int* flags            = (int*)(ws + OFF_FLAGS);

    k_init<<<1, 64, 0, stream>>>(ptrs, cnt, flags);
    k_route_ln<<<TOK, 256, 0, stream>>>(d_in[0], d_in[1], d_in[2], d_in[3], flags,
                                        hnorm, alpha, eid, cnt, bucket);
    k_plan<<<1, 64, 0, stream>>>(cnt, bucket, tiles, numTiles);
    k_ff1<<<MAXT * 64, 256, 0, stream>>>(hnorm, d_in[4], d_in[5], flags, h1,
                                         tiles, numTiles, cnt, bucket);
    k_ff2<<<MAXT * 64, 256, 0, stream>>>(h1, d_in[6], flags, part,
                                         tiles, numTiles, cnt, bucket);
    k_out<<<TOK, 256, 0, stream>>>(part, d_in[7], d_in[0], flags, alpha, eid, d_out);
}